// Round 1
// baseline (138.549 us; speedup 1.0000x reference)
//
#include <hip/hip_runtime.h>

// Problem constants (match reference)
#define NS (1 << 20)          // samples per segment
#define BLOCKS_PER_SEG 1024
#define THREADS 256
#define GRID (4 * BLOCKS_PER_SEG)

__device__ __forceinline__ float fast_tanh_pre2(float pre2) {
    // pre2 = 2*log2(e)*z ; tanh(z) = 1 - 2/(1+exp2(pre2))
    float E = __builtin_amdgcn_exp2f(pre2);
    return fmaf(-2.0f, __builtin_amdgcn_rcpf(E + 1.0f), 1.0f);
}

__global__ __launch_bounds__(THREADS) void jump_loss_stage1(
    const float* __restrict__ u0p, const float* __restrict__ u1p,
    const float* __restrict__ u2p, const float* __restrict__ u3p,
    const float* __restrict__ sW1, const float* __restrict__ sb1,
    const float* __restrict__ sW2, const float* __restrict__ sb2,
    const float* __restrict__ jW1, const float* __restrict__ jb1,
    const float* __restrict__ jW2, const float* __restrict__ jb2,
    float* __restrict__ partials, float* __restrict__ out, int use_atomic)
{
    __shared__ float s_wc[2][64], s_bb[2][64], s_u0[2][64], s_u2[2][64], s_wv[2][64];
    __shared__ float s_b2v[2];
    __shared__ float s_red[THREADS / 64];

    const int bid = blockIdx.x;
    const int seg = bid >> 10;                 // 0..3, uniform per block
    const int chunk = bid & (BLOCKS_PER_SEG - 1);
    const int tid = threadIdx.x;

    // Per-segment geometry:
    // seg 0,1 (jump_y): point (c,0); input axis ca=0, deriv axis p=1; kv=2 (py), kd2=1 (px)
    // seg 2,3 (jump_x): point (0,c); input axis ca=1, deriv axis p=0; kv=1 (px), kd2=2 (py)
    const int ca  = (seg < 2) ? 0 : 1;
    const int pp  = 1 - ca;
    const int kv  = (seg < 2) ? 2 : 1;
    const int kd2 = 3 - kv;
    const float sign  = (seg & 1) ? -1.0f : 1.0f;
    const float alpha = (seg == 0) ? 3.0f : ((seg == 3) ? -1.0f : 1.0f);
    const float beta  = (seg <  2) ? -5.0f : ((seg == 2) ? -3.0f : -7.0f);

    const float TWO_LOG2E = 2.885390081777927f; // 2*log2(e)

    // Stage folded weights into LDS (net 0 = sing, net 1 = jump)
    if (tid < 128) {
        int net = tid >> 6;
        int j = tid & 63;
        const float* W1 = net ? jW1 : sW1;
        const float* b1 = net ? jb1 : sb1;
        const float* W2 = net ? jW2 : sW2;
        float w1p = W1[pp * 64 + j];
        s_wc[net][j] = W1[ca * 64 + j] * TWO_LOG2E;
        s_bb[net][j] = b1[j] * TWO_LOG2E;
        s_u0[net][j] = w1p * W2[j * 3 + 0];
        s_u2[net][j] = w1p * W2[j * 3 + kd2];
        s_wv[net][j] = W2[j * 3 + kv];
        if (j == 0) s_b2v[net] = (net ? jb2 : sb2)[kv];
    }
    __syncthreads();

    const float* up = (seg == 0) ? u0p : (seg == 1) ? u1p : (seg == 2) ? u2p : u3p;
    float4 u4 = ((const float4*)up)[chunk * THREADS + tid];
    float uu[4] = {u4.x, u4.y, u4.z, u4.w};

    float c[4], a[4], q[4], bcv[4], rcrl[4], rcrlm1[4], wgt[4];
    #pragma unroll
    for (int s = 0; s < 4; ++s) {
        float u = uu[s];
        a[s] = u;
        c[s] = sign * u;
        float r = __builtin_amdgcn_sqrtf(fmaf(u, u, 1e-12f));
        float inv_r = __builtin_amdgcn_rcpf(r);
        float rcb = fmaxf(fmaf(-2.0f, r, 1.0f), 0.0f);   // max(1 - r/R0, 0), R0=0.5
        float rc = rcb * rcb;
        // r^(2/3) = exp2((2/3)*log2 r)
        float rl = __builtin_amdgcn_exp2f(0.66666666666667f * __builtin_amdgcn_logf(r));
        rcrl[s]   = rc * rl;
        rcrlm1[s] = rc * rl * inv_r;                     // rc * r^(l-1)
        q[s]   = u * inv_r;                              // a / r
        bcv[s] = fmaf(-u, u, 1.0f);                      // 1 - c^2
        wgt[s] = fminf(u * 40.0f, 1.0f);                 // omega = clamp(|c|/0.025, 0, 1)
    }

    float Vs[4] = {0,0,0,0}, D0s[4] = {0,0,0,0}, D2s[4] = {0,0,0,0};
    float Vj[4] = {0,0,0,0}, D0j[4] = {0,0,0,0}, D2j[4] = {0,0,0,0};

    for (int j = 0; j < 64; ++j) {
        float wc0 = s_wc[0][j], bb0 = s_bb[0][j], u00 = s_u0[0][j], u20 = s_u2[0][j], wv0 = s_wv[0][j];
        float wc1 = s_wc[1][j], bb1 = s_bb[1][j], u01 = s_u0[1][j], u21 = s_u2[1][j], wv1 = s_wv[1][j];
        #pragma unroll
        for (int s = 0; s < 4; ++s) {
            float h0 = fast_tanh_pre2(fmaf(wc0, c[s], bb0));
            float t0 = fmaf(-h0, h0, 1.0f);
            Vs[s]  = fmaf(h0, wv0, Vs[s]);
            D0s[s] = fmaf(t0, u00, D0s[s]);
            D2s[s] = fmaf(t0, u20, D2s[s]);
            float h1 = fast_tanh_pre2(fmaf(wc1, c[s], bb1));
            float t1 = fmaf(-h1, h1, 1.0f);
            Vj[s]  = fmaf(h1, wv1, Vj[s]);
            D0j[s] = fmaf(t1, u01, D0j[s]);
            D2j[s] = fmaf(t1, u21, D2j[s]);
        }
    }

    float b2s = s_b2v[0], b2j = s_b2v[1];
    float acc = 0.0f;
    #pragma unroll
    for (int s = 0; s < 4; ++s) {
        float VS = Vs[s] + b2s;
        float VJ = Vj[s] + b2j;
        float dphi1 = fmaf(D2s[s], q[s], D0s[s]) * rcrl[s]
                    + bcv[s] * fmaf(D2j[s], a[s], D0j[s]);
        float corr = VJ * bcv[s] + VS * rcrlm1[s];
        float val = alpha * dphi1 + beta * corr;
        acc = fmaf(val * val, wgt[s], acc);
    }

    // block reduction: wave shuffle then LDS
    #pragma unroll
    for (int off = 32; off; off >>= 1) acc += __shfl_down(acc, off);
    int lane = tid & 63, wid = tid >> 6;
    if (lane == 0) s_red[wid] = acc;
    __syncthreads();
    if (tid == 0) {
        float bs = s_red[0] + s_red[1] + s_red[2] + s_red[3];
        if (use_atomic) {
            atomicAdd(out, bs * (1.0f / (float)NS));
        } else {
            partials[bid] = bs;
        }
    }
}

__global__ __launch_bounds__(256) void jump_loss_stage2(
    const float* __restrict__ partials, float* __restrict__ out)
{
    double s = 0.0;
    for (int i = threadIdx.x; i < GRID; i += 256) s += (double)partials[i];
    #pragma unroll
    for (int off = 32; off; off >>= 1) s += __shfl_down(s, off);
    __shared__ double sr[4];
    int lane = threadIdx.x & 63, wid = threadIdx.x >> 6;
    if (lane == 0) sr[wid] = s;
    __syncthreads();
    if (threadIdx.x == 0) {
        out[0] = (float)((sr[0] + sr[1] + sr[2] + sr[3]) / (double)NS);
    }
}

extern "C" void kernel_launch(void* const* d_in, const int* in_sizes, int n_in,
                              void* d_out, int out_size, void* d_ws, size_t ws_size,
                              hipStream_t stream) {
    const float* u_y1  = (const float*)d_in[0];
    const float* u_ym1 = (const float*)d_in[1];
    const float* u_x1  = (const float*)d_in[2];
    const float* u_xm1 = (const float*)d_in[3];
    const float* sW1 = (const float*)d_in[4];
    const float* sb1 = (const float*)d_in[5];
    const float* sW2 = (const float*)d_in[6];
    const float* sb2 = (const float*)d_in[7];
    const float* jW1 = (const float*)d_in[8];
    const float* jb1 = (const float*)d_in[9];
    const float* jW2 = (const float*)d_in[10];
    const float* jb2 = (const float*)d_in[11];
    float* out = (float*)d_out;

    if (ws_size >= (size_t)GRID * sizeof(float)) {
        float* partials = (float*)d_ws;
        jump_loss_stage1<<<GRID, THREADS, 0, stream>>>(
            u_y1, u_ym1, u_x1, u_xm1, sW1, sb1, sW2, sb2, jW1, jb1, jW2, jb2,
            partials, out, 0);
        jump_loss_stage2<<<1, 256, 0, stream>>>(partials, out);
    } else {
        hipMemsetAsync(d_out, 0, sizeof(float), stream);
        jump_loss_stage1<<<GRID, THREADS, 0, stream>>>(
            u_y1, u_ym1, u_x1, u_xm1, sW1, sb1, sW2, sb2, jW1, jb1, jW2, jb2,
            nullptr, out, 1);
    }
}

// Round 3
// 124.608 us; speedup vs baseline: 1.1119x; 1.1119x over previous
//
#include <hip/hip_runtime.h>

// Problem constants (match reference)
#define NS (1 << 20)          // samples per segment
#define THREADS 256
#define ILP 8
#define SAMPLES_PER_BLOCK (THREADS * ILP)          // 2048
#define BLOCKS_PER_SEG (NS / SAMPLES_PER_BLOCK)    // 512
#define GRID (4 * BLOCKS_PER_SEG)                  // 2048

typedef float v2f __attribute__((ext_vector_type(2)));

__global__ __launch_bounds__(THREADS, 4) void jump_loss_stage1(
    const float* __restrict__ u0p, const float* __restrict__ u1p,
    const float* __restrict__ u2p, const float* __restrict__ u3p,
    const float* __restrict__ sW1, const float* __restrict__ sb1,
    const float* __restrict__ sW2, const float* __restrict__ sb2,
    const float* __restrict__ jW1, const float* __restrict__ jb1,
    const float* __restrict__ jW2, const float* __restrict__ jb2,
    float* __restrict__ partials, float* __restrict__ out, int use_atomic)
{
    // Row j: [wc.s, wc.j, bb.s, bb.j, w0.s, w0.j, w2.s, w2.j, wv.s, wv.j, pad, pad]
    __shared__ __align__(16) float s_w[64][12];
    __shared__ float s_swv[2];
    __shared__ float s_red[THREADS / 64];

    const int bid = blockIdx.x;
    const int seg = bid / BLOCKS_PER_SEG;            // 0..3, uniform per block
    const int chunk = bid - seg * BLOCKS_PER_SEG;
    const int tid = threadIdx.x;

    // seg 0,1 (jump_y): sample coord is x (ca=0), deriv wrt y, kv=2 (py), kd2=1 (px)
    // seg 2,3 (jump_x): sample coord is y (ca=1), deriv wrt x, kv=1 (px), kd2=2 (py)
    const int ca  = (seg < 2) ? 0 : 1;
    const int pp  = 1 - ca;
    const int kv  = (seg < 2) ? 2 : 1;
    const int kd2 = 3 - kv;
    const float sign  = (seg & 1) ? -1.0f : 1.0f;
    const float alpha = (seg == 0) ? 3.0f : ((seg == 3) ? -1.0f : 1.0f);
    const float beta  = (seg <  2) ? -5.0f : ((seg == 2) ? -3.0f : -7.0f);

    const float TL = 2.885390081777927f;             // 2*log2(e)

    if (tid < 64) {
        const int j = tid;
        float sw1c = sW1[ca * 64 + j], jw1c = jW1[ca * 64 + j];
        float sw1p = sW1[pp * 64 + j], jw1p = jW1[pp * 64 + j];
        s_w[j][0] = sw1c * TL * sign;                // sign folded: pre = wc*u + bb
        s_w[j][1] = jw1c * TL * sign;
        s_w[j][2] = sb1[j] * TL;
        s_w[j][3] = jb1[j] * TL;
        s_w[j][4] = 4.0f * sw1p * sW2[j * 3 + 0];    // x4: tp = t/4
        s_w[j][5] = 4.0f * jw1p * jW2[j * 3 + 0];
        s_w[j][6] = 4.0f * sw1p * sW2[j * 3 + kd2];
        s_w[j][7] = 4.0f * jw1p * jW2[j * 3 + kd2];
        s_w[j][8] = sW2[j * 3 + kv];
        s_w[j][9] = jW2[j * 3 + kv];
    }
    __syncthreads();
    if (tid < 2) {
        float s = 0.0f;
        for (int j = 0; j < 64; ++j) s += s_w[j][8 + tid];
        s_swv[tid] = s + (tid ? jb2[kv] : sb2[kv]);  // V = swv - 2*sum(g*wv)
    }
    __syncthreads();

    const float* up = (seg == 0) ? u0p : (seg == 1) ? u1p : (seg == 2) ? u2p : u3p;
    const float4* up4 = (const float4*)up;
    const int base = chunk * (SAMPLES_PER_BLOCK / 4) + tid;
    const float4 a4 = up4[base];
    const float4 b4 = up4[base + THREADS];
    const float uu[ILP] = {a4.x, a4.y, a4.z, a4.w, b4.x, b4.y, b4.z, b4.w};

    float Vgs[ILP], D0s[ILP], D2s[ILP], Vgj[ILP], D0j[ILP], D2j[ILP];
    #pragma unroll
    for (int s = 0; s < ILP; ++s) {
        Vgs[s] = 0.0f; D0s[s] = 0.0f; D2s[s] = 0.0f;
        Vgj[s] = 0.0f; D0j[s] = 0.0f; D2j[s] = 0.0f;
    }

    #pragma unroll 2
    for (int j = 0; j < 64; ++j) {
        const float4 A = *(const float4*)&s_w[j][0];   // wc.s, wc.j, bb.s, bb.j
        const float4 B = *(const float4*)&s_w[j][4];   // w0.s, w0.j, w2.s, w2.j
        const v2f   wv = *(const v2f*)&s_w[j][8];      // wv.s, wv.j
        #pragma unroll
        for (int s = 0; s < ILP; ++s) {
            // sing net: g = 1/(1+e^{2z}); tanh = 1-2g; (1-tanh^2)/4 = g(1-g)
            float ps = fmaf(A.x, uu[s], A.z);
            float Es = __builtin_amdgcn_exp2f(ps);
            float gs = __builtin_amdgcn_rcpf(Es + 1.0f);
            float ts = fmaf(-gs, gs, gs);
            Vgs[s] = fmaf(gs, wv.x, Vgs[s]);
            D0s[s] = fmaf(ts, B.x, D0s[s]);
            D2s[s] = fmaf(ts, B.z, D2s[s]);
            // jump net
            float pj = fmaf(A.y, uu[s], A.w);
            float Ej = __builtin_amdgcn_exp2f(pj);
            float gj = __builtin_amdgcn_rcpf(Ej + 1.0f);
            float tj = fmaf(-gj, gj, gj);
            Vgj[s] = fmaf(gj, wv.y, Vgj[s]);
            D0j[s] = fmaf(tj, B.y, D0j[s]);
            D2j[s] = fmaf(tj, B.w, D2j[s]);
        }
    }

    const float swv_s = s_swv[0], swv_j = s_swv[1];
    float acc = 0.0f;
    #pragma unroll
    for (int s = 0; s < ILP; ++s) {
        const float u = uu[s];
        float r = __builtin_amdgcn_sqrtf(fmaf(u, u, 1e-12f));
        float inv_r = __builtin_amdgcn_rcpf(r);
        float rcb = fmaxf(fmaf(-2.0f, r, 1.0f), 0.0f);   // max(1 - r/0.5, 0)
        float rc = rcb * rcb;
        float rl = __builtin_amdgcn_exp2f(0.66666666666666663f * __builtin_amdgcn_logf(r));
        float rcrl = rc * rl;                            // rc * r^(2/3)
        float rcrlm1 = rcrl * inv_r;                     // rc * r^(2/3 - 1)
        float q = u * inv_r;
        float bcv = fmaf(-u, u, 1.0f);
        float wgt = fminf(40.0f * u, 1.0f);
        float VS = fmaf(-2.0f, Vgs[s], swv_s);           // sing p_kv at point
        float VJ = fmaf(-2.0f, Vgj[s], swv_j);           // jump p_kv at point
        float dphi1 = fmaf(D2s[s], q, D0s[s]) * rcrl
                    + bcv * fmaf(D2j[s], u, D0j[s]);
        float corr = VJ * bcv + VS * rcrlm1;
        float val = fmaf(alpha, dphi1, beta * corr);
        acc = fmaf(val * val, wgt, acc);
    }

    // block reduction: wave shuffle then LDS
    #pragma unroll
    for (int off = 32; off; off >>= 1) acc += __shfl_down(acc, off);
    const int lane = tid & 63, wid = tid >> 6;
    if (lane == 0) s_red[wid] = acc;
    __syncthreads();
    if (tid == 0) {
        float bs = s_red[0] + s_red[1] + s_red[2] + s_red[3];
        if (use_atomic) {
            atomicAdd(out, bs * (1.0f / (float)NS));
        } else {
            partials[bid] = bs;
        }
    }
}

__global__ __launch_bounds__(256) void jump_loss_stage2(
    const float* __restrict__ partials, float* __restrict__ out)
{
    double s = 0.0;
    for (int i = threadIdx.x; i < GRID; i += 256) s += (double)partials[i];
    #pragma unroll
    for (int off = 32; off; off >>= 1) s += __shfl_down(s, off);
    __shared__ double sr[4];
    int lane = threadIdx.x & 63, wid = threadIdx.x >> 6;
    if (lane == 0) sr[wid] = s;
    __syncthreads();
    if (threadIdx.x == 0) {
        out[0] = (float)((sr[0] + sr[1] + sr[2] + sr[3]) / (double)NS);
    }
}

extern "C" void kernel_launch(void* const* d_in, const int* in_sizes, int n_in,
                              void* d_out, int out_size, void* d_ws, size_t ws_size,
                              hipStream_t stream) {
    const float* u_y1  = (const float*)d_in[0];
    const float* u_ym1 = (const float*)d_in[1];
    const float* u_x1  = (const float*)d_in[2];
    const float* u_xm1 = (const float*)d_in[3];
    const float* sW1 = (const float*)d_in[4];
    const float* sb1 = (const float*)d_in[5];
    const float* sW2 = (const float*)d_in[6];
    const float* sb2 = (const float*)d_in[7];
    const float* jW1 = (const float*)d_in[8];
    const float* jb1 = (const float*)d_in[9];
    const float* jW2 = (const float*)d_in[10];
    const float* jb2 = (const float*)d_in[11];
    float* out = (float*)d_out;

    if (ws_size >= (size_t)GRID * sizeof(float)) {
        float* partials = (float*)d_ws;
        jump_loss_stage1<<<GRID, THREADS, 0, stream>>>(
            u_y1, u_ym1, u_x1, u_xm1, sW1, sb1, sW2, sb2, jW1, jb1, jW2, jb2,
            partials, out, 0);
        jump_loss_stage2<<<1, 256, 0, stream>>>(partials, out);
    } else {
        hipMemsetAsync(d_out, 0, sizeof(float), stream);
        jump_loss_stage1<<<GRID, THREADS, 0, stream>>>(
            u_y1, u_ym1, u_x1, u_xm1, sW1, sb1, sW2, sb2, jW1, jb1, jW2, jb2,
            nullptr, out, 1);
    }
}

// Round 4
// 18.386 us; speedup vs baseline: 7.5355x; 6.7772x over previous
//
#include <hip/hip_runtime.h>

// Problem constants (match reference)
#define NS (1 << 20)          // samples per segment
#define THREADS 256
#define TABN 4096             // table nodes per segment (u in [0,1], h = 1/4096)

// main (interp) kernel geometry
#define MILP 16
#define MSPB (THREADS * MILP)             // 4096 samples per block
#define MBPS (NS / MSPB)                  // 256 blocks per seg
#define MGRID (4 * MBPS)                  // 1024

// build kernel geometry
#define BBPS (TABN / THREADS)             // 16 blocks per seg
#define BGRID (4 * BBPS)                  // 64

// fallback (direct) kernel geometry
#define FILP 8
#define FSPB (THREADS * FILP)
#define FBPS (NS / FSPB)                  // 512
#define FGRID (4 * FBPS)                  // 2048

#define WS_NEED ((size_t)(4096 + TABN * 4 * sizeof(float2)))

typedef float v2f __attribute__((ext_vector_type(2)));

// ---------------- shared per-segment parameterization ----------------
// seg 0: u_y1  (jump_y, sign=+1): val = 3*dphi1 - 5*corr
// seg 1: u_ym1 (jump_y, sign=-1): val = 1*dphi1 - 5*corr
// seg 2: u_x1  (jump_x, sign=+1): val = 1*dphi1 - 3*corr
// seg 3: u_xm1 (jump_x, sign=-1): val = -1*dphi1 - 7*corr
// (validated on HW in rounds 1 & 3, absmax 0.0)

// ---------------- table build: G_seg at nodes i/TABN ----------------
__global__ __launch_bounds__(THREADS) void build_tab(
    const float* __restrict__ sW1, const float* __restrict__ sb1,
    const float* __restrict__ sW2, const float* __restrict__ sb2,
    const float* __restrict__ jW1, const float* __restrict__ jb1,
    const float* __restrict__ jW2, const float* __restrict__ jb2,
    float2* __restrict__ tab)
{
    __shared__ __align__(16) float s_w[64][12];
    __shared__ float s_swv[2];

    const int bid = blockIdx.x;
    const int seg = bid / BBPS;
    const int nodeblk = bid - seg * BBPS;
    const int tid = threadIdx.x;

    const int ca  = (seg < 2) ? 0 : 1;
    const int pp  = 1 - ca;
    const int kv  = (seg < 2) ? 2 : 1;
    const int kd2 = 3 - kv;
    const float sign  = (seg & 1) ? -1.0f : 1.0f;
    const float alpha = (seg == 0) ? 3.0f : ((seg == 3) ? -1.0f : 1.0f);
    const float beta  = (seg <  2) ? -5.0f : ((seg == 2) ? -3.0f : -7.0f);

    const float TL = 2.885390081777927f;             // 2*log2(e)

    if (tid < 64) {
        const int j = tid;
        float sw1c = sW1[ca * 64 + j], jw1c = jW1[ca * 64 + j];
        float sw1p = sW1[pp * 64 + j], jw1p = jW1[pp * 64 + j];
        s_w[j][0] = sw1c * TL * sign;
        s_w[j][1] = jw1c * TL * sign;
        s_w[j][2] = sb1[j] * TL;
        s_w[j][3] = jb1[j] * TL;
        s_w[j][4] = 4.0f * sw1p * sW2[j * 3 + 0];
        s_w[j][5] = 4.0f * jw1p * jW2[j * 3 + 0];
        s_w[j][6] = 4.0f * sw1p * sW2[j * 3 + kd2];
        s_w[j][7] = 4.0f * jw1p * jW2[j * 3 + kd2];
        s_w[j][8] = sW2[j * 3 + kv];
        s_w[j][9] = jW2[j * 3 + kv];
    }
    __syncthreads();
    if (tid < 2) {
        float s = 0.0f;
        for (int j = 0; j < 64; ++j) s += s_w[j][8 + tid];
        s_swv[tid] = s + (tid ? jb2[kv] : sb2[kv]);
    }
    __syncthreads();

    const int node = nodeblk * THREADS + tid;
    const float uu[2] = {(float)node * (1.0f / TABN),
                         (float)(node + 1) * (1.0f / TABN)};

    float Vgs[2] = {0, 0}, D0s[2] = {0, 0}, D2s[2] = {0, 0};
    float Vgj[2] = {0, 0}, D0j[2] = {0, 0}, D2j[2] = {0, 0};

    for (int j = 0; j < 64; ++j) {
        const float4 A = *(const float4*)&s_w[j][0];
        const float4 B = *(const float4*)&s_w[j][4];
        const v2f   wv = *(const v2f*)&s_w[j][8];
        #pragma unroll
        for (int s = 0; s < 2; ++s) {
            float ps = fmaf(A.x, uu[s], A.z);
            float Es = __builtin_amdgcn_exp2f(ps);
            float gs = __builtin_amdgcn_rcpf(Es + 1.0f);
            float ts = fmaf(-gs, gs, gs);
            Vgs[s] = fmaf(gs, wv.x, Vgs[s]);
            D0s[s] = fmaf(ts, B.x, D0s[s]);
            D2s[s] = fmaf(ts, B.z, D2s[s]);
            float pj = fmaf(A.y, uu[s], A.w);
            float Ej = __builtin_amdgcn_exp2f(pj);
            float gj = __builtin_amdgcn_rcpf(Ej + 1.0f);
            float tj = fmaf(-gj, gj, gj);
            Vgj[s] = fmaf(gj, wv.y, Vgj[s]);
            D0j[s] = fmaf(tj, B.y, D0j[s]);
            D2j[s] = fmaf(tj, B.w, D2j[s]);
        }
    }

    const float swv_s = s_swv[0], swv_j = s_swv[1];
    float G[2];
    #pragma unroll
    for (int s = 0; s < 2; ++s) {
        const float u = uu[s];
        float r = __builtin_amdgcn_sqrtf(fmaf(u, u, 1e-12f));
        float inv_r = __builtin_amdgcn_rcpf(r);
        float rcb = fmaxf(fmaf(-2.0f, r, 1.0f), 0.0f);
        float rc = rcb * rcb;
        float rl = __builtin_amdgcn_exp2f(0.66666666666666663f * __builtin_amdgcn_logf(r));
        float rcrl = rc * rl;
        float rcrlm1 = rcrl * inv_r;
        float q = u * inv_r;
        float bcv = fmaf(-u, u, 1.0f);
        float wgt = fminf(40.0f * u, 1.0f);
        float VS = fmaf(-2.0f, Vgs[s], swv_s);
        float VJ = fmaf(-2.0f, Vgj[s], swv_j);
        float dphi1 = fmaf(D2s[s], q, D0s[s]) * rcrl
                    + bcv * fmaf(D2j[s], u, D0j[s]);
        float corr = VJ * bcv + VS * rcrlm1;
        float val = fmaf(alpha, dphi1, beta * corr);
        G[s] = val * val * wgt;
    }

    tab[seg * TABN + node] = make_float2(G[0], G[1] - G[0]);
}

// ---------------- main: LDS-staged table, linear interp ----------------
__global__ __launch_bounds__(THREADS) void eval_main(
    const float* __restrict__ u0p, const float* __restrict__ u1p,
    const float* __restrict__ u2p, const float* __restrict__ u3p,
    const float2* __restrict__ tab, float* __restrict__ partials)
{
    __shared__ __align__(16) float2 s_tab[TABN];   // 32 KiB
    __shared__ float s_red[THREADS / 64];

    const int bid = blockIdx.x;
    const int seg = bid >> 8;                      // MBPS = 256
    const int chunk = bid & 255;
    const int tid = threadIdx.x;

    // stage this segment's table into LDS (2048 float4s, 8 per thread)
    {
        const float4* src = (const float4*)(tab + seg * TABN);
        float4* dst = (float4*)s_tab;
        #pragma unroll
        for (int t = 0; t < 8; ++t)
            dst[t * THREADS + tid] = src[t * THREADS + tid];
    }
    __syncthreads();

    const float* up = (seg == 0) ? u0p : (seg == 1) ? u1p : (seg == 2) ? u2p : u3p;
    const float4* up4 = (const float4*)up;

    float acc = 0.0f;
    #pragma unroll
    for (int t = 0; t < MILP / 4; ++t) {
        float4 u4 = up4[chunk * (MSPB / 4) + t * THREADS + tid];
        float us[4] = {u4.x, u4.y, u4.z, u4.w};
        #pragma unroll
        for (int s = 0; s < 4; ++s) {
            float fidx = us[s] * (float)TABN;
            int i = (int)fidx;
            i = (i < TABN - 1) ? i : (TABN - 1);
            float f = fidx - (float)i;
            float2 T = s_tab[i];
            acc += fmaf(f, T.y, T.x);
        }
    }

    #pragma unroll
    for (int off = 32; off; off >>= 1) acc += __shfl_down(acc, off);
    const int lane = tid & 63, wid = tid >> 6;
    if (lane == 0) s_red[wid] = acc;
    __syncthreads();
    if (tid == 0) partials[bid] = s_red[0] + s_red[1] + s_red[2] + s_red[3];
}

__global__ __launch_bounds__(256) void jump_loss_stage2(
    const float* __restrict__ partials, float* __restrict__ out, int n)
{
    double s = 0.0;
    for (int i = threadIdx.x; i < n; i += 256) s += (double)partials[i];
    #pragma unroll
    for (int off = 32; off; off >>= 1) s += __shfl_down(s, off);
    __shared__ double sr[4];
    int lane = threadIdx.x & 63, wid = threadIdx.x >> 6;
    if (lane == 0) sr[wid] = s;
    __syncthreads();
    if (threadIdx.x == 0) {
        out[0] = (float)((sr[0] + sr[1] + sr[2] + sr[3]) / (double)NS);
    }
}

// ---------------- fallback: direct evaluation (R3, validated) ----------------
__global__ __launch_bounds__(THREADS, 4) void direct_stage1(
    const float* __restrict__ u0p, const float* __restrict__ u1p,
    const float* __restrict__ u2p, const float* __restrict__ u3p,
    const float* __restrict__ sW1, const float* __restrict__ sb1,
    const float* __restrict__ sW2, const float* __restrict__ sb2,
    const float* __restrict__ jW1, const float* __restrict__ jb1,
    const float* __restrict__ jW2, const float* __restrict__ jb2,
    float* __restrict__ out)
{
    __shared__ __align__(16) float s_w[64][12];
    __shared__ float s_swv[2];
    __shared__ float s_red[THREADS / 64];

    const int bid = blockIdx.x;
    const int seg = bid / FBPS;
    const int chunk = bid - seg * FBPS;
    const int tid = threadIdx.x;

    const int ca  = (seg < 2) ? 0 : 1;
    const int pp  = 1 - ca;
    const int kv  = (seg < 2) ? 2 : 1;
    const int kd2 = 3 - kv;
    const float sign  = (seg & 1) ? -1.0f : 1.0f;
    const float alpha = (seg == 0) ? 3.0f : ((seg == 3) ? -1.0f : 1.0f);
    const float beta  = (seg <  2) ? -5.0f : ((seg == 2) ? -3.0f : -7.0f);
    const float TL = 2.885390081777927f;

    if (tid < 64) {
        const int j = tid;
        float sw1c = sW1[ca * 64 + j], jw1c = jW1[ca * 64 + j];
        float sw1p = sW1[pp * 64 + j], jw1p = jW1[pp * 64 + j];
        s_w[j][0] = sw1c * TL * sign;
        s_w[j][1] = jw1c * TL * sign;
        s_w[j][2] = sb1[j] * TL;
        s_w[j][3] = jb1[j] * TL;
        s_w[j][4] = 4.0f * sw1p * sW2[j * 3 + 0];
        s_w[j][5] = 4.0f * jw1p * jW2[j * 3 + 0];
        s_w[j][6] = 4.0f * sw1p * sW2[j * 3 + kd2];
        s_w[j][7] = 4.0f * jw1p * jW2[j * 3 + kd2];
        s_w[j][8] = sW2[j * 3 + kv];
        s_w[j][9] = jW2[j * 3 + kv];
    }
    __syncthreads();
    if (tid < 2) {
        float s = 0.0f;
        for (int j = 0; j < 64; ++j) s += s_w[j][8 + tid];
        s_swv[tid] = s + (tid ? jb2[kv] : sb2[kv]);
    }
    __syncthreads();

    const float* up = (seg == 0) ? u0p : (seg == 1) ? u1p : (seg == 2) ? u2p : u3p;
    const float4* up4 = (const float4*)up;
    const int base = chunk * (FSPB / 4) + tid;
    const float4 a4 = up4[base];
    const float4 b4 = up4[base + THREADS];
    const float uu[FILP] = {a4.x, a4.y, a4.z, a4.w, b4.x, b4.y, b4.z, b4.w};

    float Vgs[FILP], D0s[FILP], D2s[FILP], Vgj[FILP], D0j[FILP], D2j[FILP];
    #pragma unroll
    for (int s = 0; s < FILP; ++s) {
        Vgs[s] = 0.0f; D0s[s] = 0.0f; D2s[s] = 0.0f;
        Vgj[s] = 0.0f; D0j[s] = 0.0f; D2j[s] = 0.0f;
    }

    #pragma unroll 2
    for (int j = 0; j < 64; ++j) {
        const float4 A = *(const float4*)&s_w[j][0];
        const float4 B = *(const float4*)&s_w[j][4];
        const v2f   wv = *(const v2f*)&s_w[j][8];
        #pragma unroll
        for (int s = 0; s < FILP; ++s) {
            float ps = fmaf(A.x, uu[s], A.z);
            float Es = __builtin_amdgcn_exp2f(ps);
            float gs = __builtin_amdgcn_rcpf(Es + 1.0f);
            float ts = fmaf(-gs, gs, gs);
            Vgs[s] = fmaf(gs, wv.x, Vgs[s]);
            D0s[s] = fmaf(ts, B.x, D0s[s]);
            D2s[s] = fmaf(ts, B.z, D2s[s]);
            float pj = fmaf(A.y, uu[s], A.w);
            float Ej = __builtin_amdgcn_exp2f(pj);
            float gj = __builtin_amdgcn_rcpf(Ej + 1.0f);
            float tj = fmaf(-gj, gj, gj);
            Vgj[s] = fmaf(gj, wv.y, Vgj[s]);
            D0j[s] = fmaf(tj, B.y, D0j[s]);
            D2j[s] = fmaf(tj, B.w, D2j[s]);
        }
    }

    const float swv_s = s_swv[0], swv_j = s_swv[1];
    float acc = 0.0f;
    #pragma unroll
    for (int s = 0; s < FILP; ++s) {
        const float u = uu[s];
        float r = __builtin_amdgcn_sqrtf(fmaf(u, u, 1e-12f));
        float inv_r = __builtin_amdgcn_rcpf(r);
        float rcb = fmaxf(fmaf(-2.0f, r, 1.0f), 0.0f);
        float rc = rcb * rcb;
        float rl = __builtin_amdgcn_exp2f(0.66666666666666663f * __builtin_amdgcn_logf(r));
        float rcrl = rc * rl;
        float rcrlm1 = rcrl * inv_r;
        float q = u * inv_r;
        float bcv = fmaf(-u, u, 1.0f);
        float wgt = fminf(40.0f * u, 1.0f);
        float VS = fmaf(-2.0f, Vgs[s], swv_s);
        float VJ = fmaf(-2.0f, Vgj[s], swv_j);
        float dphi1 = fmaf(D2s[s], q, D0s[s]) * rcrl
                    + bcv * fmaf(D2j[s], u, D0j[s]);
        float corr = VJ * bcv + VS * rcrlm1;
        float val = fmaf(alpha, dphi1, beta * corr);
        acc = fmaf(val * val, wgt, acc);
    }

    #pragma unroll
    for (int off = 32; off; off >>= 1) acc += __shfl_down(acc, off);
    const int lane = tid & 63, wid = tid >> 6;
    if (lane == 0) s_red[wid] = acc;
    __syncthreads();
    if (tid == 0) {
        float bs = s_red[0] + s_red[1] + s_red[2] + s_red[3];
        atomicAdd(out, bs * (1.0f / (float)NS));
    }
}

extern "C" void kernel_launch(void* const* d_in, const int* in_sizes, int n_in,
                              void* d_out, int out_size, void* d_ws, size_t ws_size,
                              hipStream_t stream) {
    const float* u_y1  = (const float*)d_in[0];
    const float* u_ym1 = (const float*)d_in[1];
    const float* u_x1  = (const float*)d_in[2];
    const float* u_xm1 = (const float*)d_in[3];
    const float* sW1 = (const float*)d_in[4];
    const float* sb1 = (const float*)d_in[5];
    const float* sW2 = (const float*)d_in[6];
    const float* sb2 = (const float*)d_in[7];
    const float* jW1 = (const float*)d_in[8];
    const float* jb1 = (const float*)d_in[9];
    const float* jW2 = (const float*)d_in[10];
    const float* jb2 = (const float*)d_in[11];
    float* out = (float*)d_out;

    if (ws_size >= WS_NEED) {
        float*  partials = (float*)d_ws;                       // MGRID = 1024 floats
        float2* tab = (float2*)((char*)d_ws + 4096);           // 4*TABN float2 = 128 KiB
        build_tab<<<BGRID, THREADS, 0, stream>>>(
            sW1, sb1, sW2, sb2, jW1, jb1, jW2, jb2, tab);
        eval_main<<<MGRID, THREADS, 0, stream>>>(
            u_y1, u_ym1, u_x1, u_xm1, tab, partials);
        jump_loss_stage2<<<1, 256, 0, stream>>>(partials, out, MGRID);
    } else {
        hipMemsetAsync(d_out, 0, sizeof(float), stream);
        direct_stage1<<<FGRID, THREADS, 0, stream>>>(
            u_y1, u_ym1, u_x1, u_xm1, sW1, sb1, sW2, sb2, jW1, jb1, jW2, jb2,
            out);
    }
}